// Round 2
// baseline (887.046 us; speedup 1.0000x reference)
//
#include <hip/hip_runtime.h>

// LocallyConnected1d: out[b,o,l] = sum_{c,k} x[b,c,l+k] * w[o,c,l,k] + bias[o,l]
// B=32, Cin=Cout=128, L=2048, K=3, S=1, W=2050. All fp32.
//
// Round 2: barrier-free streaming. R1 showed latency-bound weight stream
// (hbm 1.3 TB/s, VALUBusy 26%, VGPR=64 -> no load buffering; 32 barrier
// drains/block). Now: no LDS, no barriers; x read direct from global (L1/L2
// resident, ~2.3 KB per c-slice per block); weight + x double-buffered in
// registers at channel granularity so the HBM weight stream never drains.

constexpr int CIN = 128;
constexpr int LL  = 2048;
constexpr int WID = 2050;
constexpr int KK  = 3;

constexpr int TB = 4;   // batches per thread
constexpr int TO = 2;   // outputs per thread
constexpr int TL = 4;   // locations per thread
constexpr int WCS = LL * KK;       // weight channel stride (dwords) = 6144
constexpr int NTILE = 1024;        // 8 o-tiles * 128 l-tiles
constexpr int GRID = 768;          // 3 blocks/CU exact; blocks 0..255 do 2 tiles

struct WReg { float4 v[TO][3]; };  // w[o, c, l_base..+3, 0..2] : 24 dwords
struct XReg { float2 v[TB][3]; };  // x[b, c, l_base..+5]       : 24 dwords

__device__ __forceinline__ void load_w(const float* __restrict__ w,
                                       const int* woff, int coff, WReg& r) {
#pragma unroll
  for (int oi = 0; oi < TO; ++oi) {
    const float* p = w + woff[oi] + coff;   // 16B-aligned (l_base*3 % 4 == 0)
    r.v[oi][0] = *reinterpret_cast<const float4*>(p);
    r.v[oi][1] = *reinterpret_cast<const float4*>(p + 4);
    r.v[oi][2] = *reinterpret_cast<const float4*>(p + 8);
  }
}

__device__ __forceinline__ void load_x(const float* __restrict__ x,
                                       const int* xoff, int coff, XReg& r) {
#pragma unroll
  for (int bi = 0; bi < TB; ++bi) {
    const float* p = x + xoff[bi] + coff;   // 8B-aligned (WID even, l_base%4==0)
    r.v[bi][0] = *reinterpret_cast<const float2*>(p);
    r.v[bi][1] = *reinterpret_cast<const float2*>(p + 2);
    r.v[bi][2] = *reinterpret_cast<const float2*>(p + 4);
  }
}

__device__ __forceinline__ void compute(const WReg& wr, const XReg& xr,
                                        float acc[TB][TO][TL]) {
#pragma unroll
  for (int bi = 0; bi < TB; ++bi) {
    float xs[6];
    xs[0] = xr.v[bi][0].x; xs[1] = xr.v[bi][0].y;
    xs[2] = xr.v[bi][1].x; xs[3] = xr.v[bi][1].y;
    xs[4] = xr.v[bi][2].x; xs[5] = xr.v[bi][2].y;
#pragma unroll
    for (int oi = 0; oi < TO; ++oi) {
      const float* wf = reinterpret_cast<const float*>(&wr.v[oi][0]);
#pragma unroll
      for (int j = 0; j < TL; ++j)
#pragma unroll
        for (int k = 0; k < KK; ++k)
          acc[bi][oi][j] = fmaf(wf[j * KK + k], xs[j + k], acc[bi][oi][j]);
    }
  }
}

__global__ __launch_bounds__(256, 3)
void lc1d(const float* __restrict__ x, const float* __restrict__ w,
          const float* __restrict__ bias, float* __restrict__ out) {
  const int tid = threadIdx.x;
  const int lg = tid & 3;          // 4 l-groups of TL=4
  const int og = (tid >> 2) & 7;   // 8 o-groups of TO=2
  const int bg = tid >> 5;         // 8 b-groups of TB=4

#pragma unroll 1
  for (int tile = blockIdx.x; tile < NTILE; tile += GRID) {
    const int L0 = (tile & 127) * 16;
    const int o_base = (tile >> 7) * 16 + og * TO;
    const int l_base = L0 + lg * TL;
    const int b_base = bg * TB;

    int woff[TO], xoff[TB];
#pragma unroll
    for (int oi = 0; oi < TO; ++oi)
      woff[oi] = (o_base + oi) * (CIN * WCS) + l_base * KK;
#pragma unroll
    for (int bi = 0; bi < TB; ++bi)
      xoff[bi] = (b_base + bi) * (CIN * WID) + l_base;

    // accumulators init with bias (same bias across batch)
    float acc[TB][TO][TL];
#pragma unroll
    for (int oi = 0; oi < TO; ++oi) {
      const float4 bv =
          *reinterpret_cast<const float4*>(&bias[(o_base + oi) * LL + l_base]);
#pragma unroll
      for (int bi = 0; bi < TB; ++bi) {
        acc[bi][oi][0] = bv.x; acc[bi][oi][1] = bv.y;
        acc[bi][oi][2] = bv.z; acc[bi][oi][3] = bv.w;
      }
    }

    WReg wA, wB;
    XReg xA, xB;
    load_w(w, woff, 0, wA);        load_x(x, xoff, 0, xA);
    load_w(w, woff, WCS, wB);      load_x(x, xoff, WID, xB);

#pragma unroll 1
    for (int c0 = 0; c0 < CIN; c0 += 2) {
      // clamp keeps tail prefetches in-bounds (harmless reload of c=0/1)
      const int cA = (c0 + 2 < CIN) ? (c0 + 2) : 0;
      const int cB = (c0 + 3 < CIN) ? (c0 + 3) : 1;
      compute(wA, xA, acc);                         // consume stage A (c0)
      load_w(w, woff, cA * WCS, wA);                // refill A -> flies during B
      load_x(x, xoff, cA * WID, xA);
      compute(wB, xB, acc);                         // consume stage B (c0+1)
      load_w(w, woff, cB * WCS, wB);                // refill B -> flies during A
      load_x(x, xoff, cB * WID, xB);
    }

    // store out[b, o, l_base..+3]
#pragma unroll
    for (int bi = 0; bi < TB; ++bi) {
      const int b = b_base + bi;
#pragma unroll
      for (int oi = 0; oi < TO; ++oi) {
        const float4 v = make_float4(acc[bi][oi][0], acc[bi][oi][1],
                                     acc[bi][oi][2], acc[bi][oi][3]);
        *reinterpret_cast<float4*>(
            &out[(b * CIN + (o_base + oi)) * LL + l_base]) = v;
      }
    }
  }
}

extern "C" void kernel_launch(void* const* d_in, const int* in_sizes, int n_in,
                              void* d_out, int out_size, void* d_ws, size_t ws_size,
                              hipStream_t stream) {
  const float* x    = (const float*)d_in[0];
  const float* wgt  = (const float*)d_in[1];
  const float* bias = (const float*)d_in[2];
  float* out = (float*)d_out;
  hipLaunchKernelGGL(lc1d, dim3(GRID), dim3(256), 0, stream, x, wgt, bias, out);
}